// Round 1
// baseline (4735.974 us; speedup 1.0000x reference)
//
#include <hip/hip_runtime.h>
#include <cmath>

#define BATCH 512
#define NN 32
#define NVT 32
#define HS 501
#define VS 533      // HS + NN
#define G3 1503     // 3*HS

#define BM 32       // batch rows per block
#define BK 32       // k-chunk
#define BH 32       // out cols per (gate/mat) per block

__device__ __forceinline__ float sigmoidf_(float x) {
    return 1.0f / (1.0f + __expf(-x));
}
__device__ __forceinline__ float tanhf_(float x) {
    // tanh(x) = 1 - 2/(1+exp(2x)); saturates correctly for |x| large
    return 1.0f - 2.0f / (1.0f + __expf(2.0f * x));
}

// Step kernel 1: gh = Msg_v @ W_hh^T  (+GRU epilogue) -> Hv
// grid (16,16), block 256
__global__ __launch_bounds__(256) void gru_kernel(
    const float* __restrict__ Msg,    // [NN][BATCH][HS]
    const float* __restrict__ W_hh,   // [G3][HS]
    const float* __restrict__ b_hh,   // [G3]
    const float* __restrict__ W_ih,   // [G3][NVT]
    const float* __restrict__ b_ih,   // [G3]
    const int*   __restrict__ types,  // [BATCH][NN]
    float* __restrict__ Hv,           // [BATCH][HS]
    int v)
{
    __shared__ float At[BK][BM + 1];         // [k][b]
    __shared__ float Wt[3][BK][BH + 1];      // [gate][k][h]
    const float* A = Msg + (size_t)v * BATCH * HS;
    const int bb = blockIdx.x * BM;
    const int hb = blockIdx.y * BH;
    const int t  = threadIdx.x;
    const int tx = t & 15, ty = t >> 4;

    float acc[3][2][2] = {};

    for (int k0 = 0; k0 < HS; k0 += BK) {
        #pragma unroll
        for (int i = 0; i < 4; i++) {
            int idx = t + i * 256;
            int r = idx >> 5, c = idx & 31;
            int k = k0 + c;
            At[c][r] = (k < HS) ? A[(size_t)(bb + r) * HS + k] : 0.0f;
        }
        #pragma unroll
        for (int g = 0; g < 3; g++) {
            #pragma unroll
            for (int i = 0; i < 4; i++) {
                int idx = t + i * 256;
                int r = idx >> 5, c = idx & 31;   // r: out col, c: k
                int h = hb + r, k = k0 + c;
                Wt[g][c][r] = (h < HS && k < HS)
                    ? W_hh[(size_t)(g * HS + h) * HS + k] : 0.0f;
            }
        }
        __syncthreads();
        #pragma unroll
        for (int kk = 0; kk < BK; kk++) {
            float a0 = At[kk][ty * 2 + 0];
            float a1 = At[kk][ty * 2 + 1];
            #pragma unroll
            for (int g = 0; g < 3; g++) {
                float w0 = Wt[g][kk][tx * 2 + 0];
                float w1 = Wt[g][kk][tx * 2 + 1];
                acc[g][0][0] += a0 * w0; acc[g][0][1] += a0 * w1;
                acc[g][1][0] += a1 * w0; acc[g][1][1] += a1 * w1;
            }
        }
        __syncthreads();
    }

    #pragma unroll
    for (int bi = 0; bi < 2; bi++) {
        int b = bb + ty * 2 + bi;
        int typ = types[b * NN + v];
        #pragma unroll
        for (int ci = 0; ci < 2; ci++) {
            int h = hb + tx * 2 + ci;
            if (h >= HS) continue;
            float gir = W_ih[(size_t)(0 * HS + h) * NVT + typ] + b_ih[0 * HS + h];
            float giz = W_ih[(size_t)(1 * HS + h) * NVT + typ] + b_ih[1 * HS + h];
            float gin = W_ih[(size_t)(2 * HS + h) * NVT + typ] + b_ih[2 * HS + h];
            float ghr = acc[0][bi][ci] + b_hh[0 * HS + h];
            float ghz = acc[1][bi][ci] + b_hh[1 * HS + h];
            float ghn = acc[2][bi][ci] + b_hh[2 * HS + h];
            float r = sigmoidf_(gir + ghr);
            float z = sigmoidf_(giz + ghz);
            float n = tanhf_(gin + r * ghn);
            float hmsg = A[(size_t)b * HS + h];
            Hv[(size_t)b * HS + h] = (1.0f - z) * n + z * hmsg;
        }
    }
}

// Step kernel 2: zg/zm = Hv @ {Wg,Wm}[:, :HS]^T ; G = sigmoid(zg+id+bg)*(zm+id);
// scatter Msg[v'] += adj[b,v,v'] * G for v' > v.
// grid (16,16), block 256
__global__ __launch_bounds__(256) void gate_kernel(
    const float* __restrict__ Hv,    // [BATCH][HS]
    const float* __restrict__ Wg,    // [HS][VS]
    const float* __restrict__ bg,    // [HS]
    const float* __restrict__ Wm,    // [HS][VS]
    const float* __restrict__ adj,   // [BATCH][NN][NN]
    float* __restrict__ Msg,         // [NN][BATCH][HS]
    int v)
{
    __shared__ float At[BK][BM + 1];
    __shared__ float Wt[2][BK][BH + 1];
    const int bb = blockIdx.x * BM;
    const int hb = blockIdx.y * BH;
    const int t  = threadIdx.x;
    const int tx = t & 15, ty = t >> 4;

    float acc[2][2][2] = {};

    for (int k0 = 0; k0 < HS; k0 += BK) {
        #pragma unroll
        for (int i = 0; i < 4; i++) {
            int idx = t + i * 256;
            int r = idx >> 5, c = idx & 31;
            int k = k0 + c;
            At[c][r] = (k < HS) ? Hv[(size_t)(bb + r) * HS + k] : 0.0f;
        }
        #pragma unroll
        for (int i = 0; i < 4; i++) {
            int idx = t + i * 256;
            int r = idx >> 5, c = idx & 31;
            int h = hb + r, k = k0 + c;
            Wt[0][c][r] = (h < HS && k < HS) ? Wg[(size_t)h * VS + k] : 0.0f;
            Wt[1][c][r] = (h < HS && k < HS) ? Wm[(size_t)h * VS + k] : 0.0f;
        }
        __syncthreads();
        #pragma unroll
        for (int kk = 0; kk < BK; kk++) {
            float a0 = At[kk][ty * 2 + 0];
            float a1 = At[kk][ty * 2 + 1];
            #pragma unroll
            for (int m = 0; m < 2; m++) {
                float w0 = Wt[m][kk][tx * 2 + 0];
                float w1 = Wt[m][kk][tx * 2 + 1];
                acc[m][0][0] += a0 * w0; acc[m][0][1] += a0 * w1;
                acc[m][1][0] += a1 * w0; acc[m][1][1] += a1 * w1;
            }
        }
        __syncthreads();
    }

    // compute G and scatter
    float gv[2][2];
    #pragma unroll
    for (int bi = 0; bi < 2; bi++) {
        #pragma unroll
        for (int ci = 0; ci < 2; ci++) {
            int h = hb + tx * 2 + ci;
            if (h >= HS) { gv[bi][ci] = 0.0f; continue; }
            float zg = acc[0][bi][ci] + Wg[(size_t)h * VS + HS + v] + bg[h];
            float zm = acc[1][bi][ci] + Wm[(size_t)h * VS + HS + v];
            gv[bi][ci] = sigmoidf_(zg) * zm;
        }
    }
    for (int vp = v + 1; vp < NN; vp++) {
        float* Mp = Msg + (size_t)vp * BATCH * HS;
        #pragma unroll
        for (int bi = 0; bi < 2; bi++) {
            int b = bb + ty * 2 + bi;
            float a = adj[((size_t)b * NN + v) * NN + vp];
            if (a != 0.0f) {
                #pragma unroll
                for (int ci = 0; ci < 2; ci++) {
                    int h = hb + tx * 2 + ci;
                    if (h < HS) Mp[(size_t)b * HS + h] += a * gv[bi][ci];
                }
            }
        }
    }
}

// Final: mu = Hv31 @ W_reg^T + b_reg
__global__ __launch_bounds__(256) void final_kernel(
    const float* __restrict__ Hv,     // [BATCH][HS]
    const float* __restrict__ W_reg,  // [NN][HS]
    const float* __restrict__ b_reg,  // [NN]
    float* __restrict__ out)          // [BATCH][NN]
{
    int idx = blockIdx.x * 256 + threadIdx.x;
    if (idx >= BATCH * NN) return;
    int b = idx >> 5, i = idx & 31;
    float s = b_reg[i];
    const float* hrow = Hv + (size_t)b * HS;
    const float* wrow = W_reg + (size_t)i * HS;
    for (int k = 0; k < HS; k++) s += hrow[k] * wrow[k];
    out[idx] = s;
}

extern "C" void kernel_launch(void* const* d_in, const int* in_sizes, int n_in,
                              void* d_out, int out_size, void* d_ws, size_t ws_size,
                              hipStream_t stream) {
    const int*   node_types = (const int*)  d_in[0];
    const float* adj        = (const float*)d_in[1];
    const float* Wg         = (const float*)d_in[2];
    const float* bg         = (const float*)d_in[3];
    const float* Wm         = (const float*)d_in[4];
    const float* W_ih       = (const float*)d_in[5];
    const float* b_ih       = (const float*)d_in[6];
    const float* W_hh       = (const float*)d_in[7];
    const float* b_hh       = (const float*)d_in[8];
    const float* W_reg      = (const float*)d_in[9];
    const float* b_reg      = (const float*)d_in[10];
    float* out = (float*)d_out;

    float* Msg = (float*)d_ws;                         // [NN][BATCH][HS]
    float* Hv  = Msg + (size_t)NN * BATCH * HS;        // [BATCH][HS]

    hipMemsetAsync(Msg, 0, (size_t)NN * BATCH * HS * sizeof(float), stream);

    dim3 blk(256);
    dim3 grd(BATCH / BM, (HS + BH - 1) / BH);   // 16 x 16
    for (int v = 0; v < NN; v++) {
        gru_kernel<<<grd, blk, 0, stream>>>(Msg, W_hh, b_hh, W_ih, b_ih,
                                            node_types, Hv, v);
        if (v < NN - 1) {
            gate_kernel<<<grd, blk, 0, stream>>>(Hv, Wg, bg, Wm, adj, Msg, v);
        }
    }
    final_kernel<<<(BATCH * NN + 255) / 256, 256, 0, stream>>>(Hv, W_reg, b_reg, out);
}

// Round 2
// 802.035 us; speedup vs baseline: 5.9049x; 5.9049x over previous
//
#include <hip/hip_runtime.h>

#define BATCH 512
#define NN    32
#define NVT   32
#define HS    501
#define VS    533
#define KP    512   // padded K / H dimension

typedef short bf16x8 __attribute__((ext_vector_type(8)));
typedef float f32x4  __attribute__((ext_vector_type(4)));

__device__ __forceinline__ unsigned short f2bf(float f) {
    unsigned int u = __float_as_uint(f);
    u += 0x7fffu + ((u >> 16) & 1u);       // round-to-nearest-even
    return (unsigned short)(u >> 16);
}
__device__ __forceinline__ float bf2f(unsigned short s) {
    return __uint_as_float(((unsigned int)s) << 16);
}
__device__ __forceinline__ float sigmoidf_(float x) { return 1.0f / (1.0f + __expf(-x)); }
__device__ __forceinline__ float tanhf_(float x)    { return 1.0f - 2.0f / (1.0f + __expf(2.0f * x)); }

#define N_WHH  (3 * KP * KP)
#define N_WGM  (2 * KP * KP)
#define N_GI   (3 * NVT * KP)
#define N_MSG  (BATCH * KP)
#define N_WREG (NN * KP)
#define N_TOT  (N_WHH + N_WGM + N_GI + N_MSG + N_WREG)

// One-time per launch: bf16 weight repack (zero-padded to 512), gi table, Msg zero.
__global__ void prep_kernel(const float* __restrict__ W_hh, const float* __restrict__ Wg,
                            const float* __restrict__ Wm, const float* __restrict__ W_ih,
                            const float* __restrict__ b_ih, const float* __restrict__ W_reg,
                            unsigned short* __restrict__ Whh_bf, unsigned short* __restrict__ Wgm_bf,
                            float* __restrict__ gi_tab, float* __restrict__ Msg,
                            float* __restrict__ Wreg_pad)
{
    for (int i = blockIdx.x * blockDim.x + threadIdx.x; i < N_TOT; i += gridDim.x * blockDim.x) {
        int j = i;
        if (j < N_WHH) {
            int g = j >> 18, rem = j & (KP * KP - 1);
            int h = rem >> 9, k = rem & (KP - 1);
            Whh_bf[j] = (h < HS && k < HS) ? f2bf(W_hh[(size_t)(g * HS + h) * HS + k])
                                           : (unsigned short)0;
            continue;
        }
        j -= N_WHH;
        if (j < N_WGM) {
            int m = j >> 18, rem = j & (KP * KP - 1);
            int h = rem >> 9, k = rem & (KP - 1);
            const float* src = m ? Wm : Wg;
            Wgm_bf[j] = (h < HS && k < HS) ? f2bf(src[(size_t)h * VS + k]) : (unsigned short)0;
            continue;
        }
        j -= N_WGM;
        if (j < N_GI) {
            int g = j / (NVT * KP), rem = j % (NVT * KP);
            int typ = rem >> 9, h = rem & (KP - 1);
            gi_tab[j] = (h < HS) ? (W_ih[(size_t)(g * HS + h) * NVT + typ] + b_ih[g * HS + h]) : 0.0f;
            continue;
        }
        j -= N_GI;
        if (j < N_MSG) { Msg[j] = 0.0f; continue; }
        j -= N_MSG;
        {
            int r = j >> 9, k = j & (KP - 1);
            Wreg_pad[j] = (k < HS) ? W_reg[(size_t)r * HS + k] : 0.0f;
        }
    }
}

// gh = Msg_v @ W_hh^T (3 gates), split-K over 4 waves, + GRU epilogue -> Hv (f32 + bf16)
__global__ __launch_bounds__(256, 4) void gru_kernel(
    const float* __restrict__ Msg,             // [512][512] f32, padded
    const unsigned short* __restrict__ Whh,    // [3][512][512] bf16
    const float* __restrict__ gi_tab,          // [3][32][512]
    const float* __restrict__ b_hh,            // [1503]
    const int* __restrict__ types,             // [512][32]
    float* __restrict__ Hv,                    // [512][512]
    unsigned short* __restrict__ Hvb,          // [512][512] bf16
    int v)
{
    __shared__ float part[4][3][256];
    const int t = threadIdx.x;
    const int wave = t >> 6, lane = t & 63;
    const int row16 = lane & 15, kgrp = lane >> 4;
    const int bb = blockIdx.x * 16, hb = blockIdx.y * 16;

    f32x4 acc0 = {0.f, 0.f, 0.f, 0.f};
    f32x4 acc1 = {0.f, 0.f, 0.f, 0.f};
    f32x4 acc2 = {0.f, 0.f, 0.f, 0.f};
    const float* Arow = Msg + (size_t)(bb + row16) * KP;
    const unsigned short* B0 = Whh + (size_t)(0 * KP + hb + row16) * KP;
    const unsigned short* B1 = Whh + (size_t)(1 * KP + hb + row16) * KP;
    const unsigned short* B2 = Whh + (size_t)(2 * KP + hb + row16) * KP;
    const int kb = wave * 128 + kgrp * 8;

    #pragma unroll
    for (int kk = 0; kk < 4; kk++) {
        const int k = kb + kk * 32;
        f32x4 a0 = *(const f32x4*)(Arow + k);
        f32x4 a1 = *(const f32x4*)(Arow + k + 4);
        bf16x8 af;
        af[0] = (short)f2bf(a0[0]); af[1] = (short)f2bf(a0[1]);
        af[2] = (short)f2bf(a0[2]); af[3] = (short)f2bf(a0[3]);
        af[4] = (short)f2bf(a1[0]); af[5] = (short)f2bf(a1[1]);
        af[6] = (short)f2bf(a1[2]); af[7] = (short)f2bf(a1[3]);
        bf16x8 w0 = *(const bf16x8*)(B0 + k);
        bf16x8 w1 = *(const bf16x8*)(B1 + k);
        bf16x8 w2 = *(const bf16x8*)(B2 + k);
        acc0 = __builtin_amdgcn_mfma_f32_16x16x32_bf16(af, w0, acc0, 0, 0, 0);
        acc1 = __builtin_amdgcn_mfma_f32_16x16x32_bf16(af, w1, acc1, 0, 0, 0);
        acc2 = __builtin_amdgcn_mfma_f32_16x16x32_bf16(af, w2, acc2, 0, 0, 0);
    }

    #pragma unroll
    for (int j = 0; j < 4; j++) {
        const int pi = (kgrp * 4 + j) * 16 + row16;   // D: row=4*(l>>4)+reg, col=l&15
        part[wave][0][pi] = acc0[j];
        part[wave][1][pi] = acc1[j];
        part[wave][2][pi] = acc2[j];
    }
    __syncthreads();

    const int r = t >> 4, c = t & 15;
    const int b = bb + r, h = hb + c;
    const float s0 = part[0][0][t] + part[1][0][t] + part[2][0][t] + part[3][0][t];
    const float s1 = part[0][1][t] + part[1][1][t] + part[2][1][t] + part[3][1][t];
    const float s2 = part[0][2][t] + part[1][2][t] + part[2][2][t] + part[3][2][t];

    float hv = 0.0f;
    if (h < HS) {
        const int typ = types[b * NN + v];
        const float gir = gi_tab[(size_t)(0 * NVT + typ) * KP + h];
        const float giz = gi_tab[(size_t)(1 * NVT + typ) * KP + h];
        const float gin = gi_tab[(size_t)(2 * NVT + typ) * KP + h];
        const float rg = sigmoidf_(gir + s0 + b_hh[h]);
        const float zg = sigmoidf_(giz + s1 + b_hh[HS + h]);
        const float ng = tanhf_(gin + rg * (s2 + b_hh[2 * HS + h]));
        const float hmsg = Msg[(size_t)b * KP + h];
        hv = (1.0f - zg) * ng + zg * hmsg;
    }
    Hv[(size_t)b * KP + h] = hv;
    Hvb[(size_t)b * KP + h] = f2bf(hv);
}

// zg/zm = Hv @ {Wg,Wm}^T, split-K over 4 waves; epilogue: G_v = sigmoid(zg+idg+bg)*(zm+idm),
// write G_v (bf16), gather-assemble Msg_{v+1} = sum_{u<=v} adj[b,u,v+1]*G_u.
__global__ __launch_bounds__(256, 4) void gate_kernel(
    const unsigned short* __restrict__ Hvb,    // [512][512] bf16
    const unsigned short* __restrict__ Wgm,    // [2][512][512] bf16
    const float* __restrict__ Wg,              // [501][533] f32 (identity cols)
    const float* __restrict__ Wm,
    const float* __restrict__ bg,
    const float* __restrict__ adj,             // [512][32][32]
    unsigned short* __restrict__ Gbuf,         // [32][512][512] bf16
    float* __restrict__ Msg,                   // [512][512] f32 (next step's input)
    int v)
{
    __shared__ float part[4][2][256];
    const int t = threadIdx.x;
    const int wave = t >> 6, lane = t & 63;
    const int row16 = lane & 15, kgrp = lane >> 4;
    const int bb = blockIdx.x * 16, hb = blockIdx.y * 16;

    f32x4 acc0 = {0.f, 0.f, 0.f, 0.f};
    f32x4 acc1 = {0.f, 0.f, 0.f, 0.f};
    const unsigned short* Arow = Hvb + (size_t)(bb + row16) * KP;
    const unsigned short* B0 = Wgm + (size_t)(hb + row16) * KP;
    const unsigned short* B1 = Wgm + (size_t)(KP + hb + row16) * KP;
    const int kb = wave * 128 + kgrp * 8;

    #pragma unroll
    for (int kk = 0; kk < 4; kk++) {
        const int k = kb + kk * 32;
        bf16x8 af = *(const bf16x8*)(Arow + k);
        bf16x8 w0 = *(const bf16x8*)(B0 + k);
        bf16x8 w1 = *(const bf16x8*)(B1 + k);
        acc0 = __builtin_amdgcn_mfma_f32_16x16x32_bf16(af, w0, acc0, 0, 0, 0);
        acc1 = __builtin_amdgcn_mfma_f32_16x16x32_bf16(af, w1, acc1, 0, 0, 0);
    }

    #pragma unroll
    for (int j = 0; j < 4; j++) {
        const int pi = (kgrp * 4 + j) * 16 + row16;
        part[wave][0][pi] = acc0[j];
        part[wave][1][pi] = acc1[j];
    }
    __syncthreads();

    const int r = t >> 4, c = t & 15;
    const int b = bb + r, h = hb + c;
    const float s0 = part[0][0][t] + part[1][0][t] + part[2][0][t] + part[3][0][t];
    const float s1 = part[0][1][t] + part[1][1][t] + part[2][1][t] + part[3][1][t];

    float gq = 0.0f;
    if (h < HS) {
        const float zg = s0 + Wg[(size_t)h * VS + HS + v] + bg[h];
        const float zm = s1 + Wm[(size_t)h * VS + HS + v];
        gq = sigmoidf_(zg) * zm;
    }
    const unsigned short gbits = f2bf(gq);
    Gbuf[((size_t)v * BATCH + b) * KP + h] = gbits;

    // assemble Msg for node v+1 (gather over predecessors u <= v)
    float m = 0.0f;
    const float* acol = adj + (size_t)b * NN * NN + (v + 1);
    for (int u = 0; u < v; u++) {
        const float a = acol[u * NN];
        if (a != 0.0f) m += a * bf2f(Gbuf[((size_t)u * BATCH + b) * KP + h]);
    }
    const float aself = acol[v * NN];
    if (aself != 0.0f) m += aself * bf2f(gbits);
    Msg[(size_t)b * KP + h] = m;
}

// mu = Hv31 @ W_reg^T + b_reg
__global__ __launch_bounds__(256) void final_kernel(
    const float* __restrict__ Hv,        // [512][512]
    const float* __restrict__ Wreg_pad,  // [32][512]
    const float* __restrict__ b_reg,     // [32]
    float* __restrict__ out)             // [512][32]
{
    const int idx = blockIdx.x * 256 + threadIdx.x;
    const int b = idx >> 5, i = idx & 31;
    const f32x4* hp = (const f32x4*)(Hv + (size_t)b * KP);
    const f32x4* wp = (const f32x4*)(Wreg_pad + (size_t)i * KP);
    f32x4 s = {0.f, 0.f, 0.f, 0.f};
    #pragma unroll 8
    for (int k = 0; k < KP / 4; k++) s += hp[k] * wp[k];
    out[idx] = s[0] + s[1] + s[2] + s[3] + b_reg[i];
}

extern "C" void kernel_launch(void* const* d_in, const int* in_sizes, int n_in,
                              void* d_out, int out_size, void* d_ws, size_t ws_size,
                              hipStream_t stream) {
    const int*   node_types = (const int*)  d_in[0];
    const float* adj        = (const float*)d_in[1];
    const float* Wg         = (const float*)d_in[2];
    const float* bg         = (const float*)d_in[3];
    const float* Wm         = (const float*)d_in[4];
    const float* W_ih       = (const float*)d_in[5];
    const float* b_ih       = (const float*)d_in[6];
    const float* W_hh       = (const float*)d_in[7];
    const float* b_hh       = (const float*)d_in[8];
    const float* W_reg      = (const float*)d_in[9];
    const float* b_reg      = (const float*)d_in[10];
    float* out = (float*)d_out;

    char* p = (char*)d_ws;
    unsigned short* Gbuf   = (unsigned short*)p; p += (size_t)NN * BATCH * KP * 2;  // 16.78 MB
    unsigned short* Hvb    = (unsigned short*)p; p += (size_t)BATCH * KP * 2;       // 0.52 MB
    unsigned short* Whh_bf = (unsigned short*)p; p += (size_t)3 * KP * KP * 2;      // 1.57 MB
    unsigned short* Wgm_bf = (unsigned short*)p; p += (size_t)2 * KP * KP * 2;      // 1.05 MB
    float* Msg      = (float*)p; p += (size_t)BATCH * KP * 4;                        // 1.05 MB
    float* Hv       = (float*)p; p += (size_t)BATCH * KP * 4;                        // 1.05 MB
    float* gi_tab   = (float*)p; p += (size_t)3 * NVT * KP * 4;                      // 0.20 MB
    float* Wreg_pad = (float*)p; p += (size_t)NN * KP * 4;                           // 0.07 MB

    prep_kernel<<<2048, 256, 0, stream>>>(W_hh, Wg, Wm, W_ih, b_ih, W_reg,
                                          Whh_bf, Wgm_bf, gi_tab, Msg, Wreg_pad);

    dim3 grd(BATCH / 16, KP / 16);   // 32 x 32 = 1024 blocks
    for (int v = 0; v < NN; v++) {
        gru_kernel<<<grd, 256, 0, stream>>>(Msg, Whh_bf, gi_tab, b_hh, node_types, Hv, Hvb, v);
        if (v < NN - 1)
            gate_kernel<<<grd, 256, 0, stream>>>(Hvb, Wgm_bf, Wg, Wm, bg, adj, Gbuf, Msg, v);
    }
    final_kernel<<<(BATCH * NN) / 256, 256, 0, stream>>>(Hv, Wreg_pad, b_reg, out);
}